// Round 1
// baseline (1524.567 us; speedup 1.0000x reference)
//
#include <hip/hip_runtime.h>
#include <hip/hip_bf16.h>

// SSD multibox loss for MI355X.
// d_in[0] = y_pred [B,A,85] f32, d_in[1] = y_true [B,A,85] f32 (one-hot cls + 4 box)
// out: single f32 scalar.
//
// Plan: one streaming pass (kMain) computes per-anchor conf/masks/smooth-L1,
// emits a monotone uint32 key per negative anchor + a 16-bit-prefix histogram;
// radix-select kernels find the exact top-K threshold; final pass sums.

#define SLOT 85
#define NCLS 81
#define TILE 64
#define NSHARD 4
#define NEG_POS_RATIO_F 3.0f

struct Scalars {
    double pos_sum;
    double loc_sum;
    double neg_sum;
    unsigned npos;
    unsigned selP;
    unsigned K1;
    unsigned T;
    unsigned mode;   // 0 = refine, 1 = T already final
    unsigned pad[3];
};

__device__ inline unsigned f2k(float f) {
    unsigned b = __float_as_uint(f);
    return (b & 0x80000000u) ? ~b : (b | 0x80000000u);
}
__device__ inline float k2f(unsigned k) {
    unsigned b = (k & 0x80000000u) ? (k & 0x7FFFFFFFu) : ~k;
    return __uint_as_float(b);
}
__device__ inline void atomAddD(double* p, double v) {
    unsafeAtomicAdd(p, v);   // native global_atomic_add_f64 on gfx950
}

// ---------------- main streaming pass ----------------
// Block = 256 threads, tile = 64 anchors = 5440 floats per tensor.
// Stage coalesced float4, compute product / smooth-L1 elementwise into LDS,
// then 4 threads per anchor reduce.
__global__ __launch_bounds__(256) void kMain(
    const float* __restrict__ yp, const float* __restrict__ yt,
    unsigned* __restrict__ keys, unsigned* __restrict__ hist,
    Scalars* __restrict__ sc, int nAnchor)
{
    __shared__ alignas(16) float v[TILE * SLOT];   // 21760 B
    __shared__ float t0[TILE];
    __shared__ int   posf[TILE];
    __shared__ float rbuf[12];

    const int tid = threadIdx.x;
    const long long base  = (long long)blockIdx.x * (TILE * SLOT);
    const long long total = (long long)nAnchor * SLOT;

    if (tid < TILE) posf[tid] = 0;
    __syncthreads();

    // ---- stage: coalesced float4, incremental (class, anchor) tracking ----
    {
        int i = tid * 4;
        int adiv = i / SLOT;          // local anchor of element i
        int c    = i - adiv * SLOT;   // class slot of element i
        while (i < TILE * SLOT) {
            float ytv[4], ypv[4];
            if (base + i + 3 < total) {
                float4 a4 = *reinterpret_cast<const float4*>(yt + base + i);
                float4 p4 = *reinterpret_cast<const float4*>(yp + base + i);
                ytv[0]=a4.x; ytv[1]=a4.y; ytv[2]=a4.z; ytv[3]=a4.w;
                ypv[0]=p4.x; ypv[1]=p4.y; ypv[2]=p4.z; ypv[3]=p4.w;
            } else {
                #pragma unroll
                for (int l = 0; l < 4; ++l) {
                    ytv[l] = (base + i + l < total) ? yt[base + i + l] : 0.0f;
                    ypv[l] = (base + i + l < total) ? yp[base + i + l] : 0.0f;
                }
            }
            float ov[4];
            #pragma unroll
            for (int l = 0; l < 4; ++l) {
                int cl = c + l, al = adiv;
                if (cl >= SLOT) { cl -= SLOT; al += 1; }
                float a = ytv[l], p = ypv[l];
                float val;
                if (cl < NCLS) {
                    val = a * p;                    // conf contribution
                } else {
                    float d = p - a;                // smooth-L1 contribution
                    float ad = fabsf(d);
                    val = (ad < 1.0f) ? 0.5f * d * d : (ad - 0.5f);
                }
                ov[l] = val;
                if (cl == 0) t0[al] = a;
                else if (cl < NCLS && a != 0.0f) posf[al] = 1;
            }
            *reinterpret_cast<float4*>(&v[i]) = make_float4(ov[0], ov[1], ov[2], ov[3]);
            i += 1024;
            c += 4; adiv += 12;
            if (c >= SLOT) { c -= SLOT; adiv += 1; }
        }
    }
    __syncthreads();

    // ---- reduce: 4 threads per anchor ----
    const int aIdx = tid >> 2, j = tid & 3;
    float cs = 0.0f, ls = 0.0f;
    #pragma unroll
    for (int c = j; c < SLOT; c += 4) {
        float x = v[aIdx * SLOT + c];
        if (c < NCLS) cs += x; else ls += x;
    }
    cs += __shfl_xor(cs, 1); cs += __shfl_xor(cs, 2);
    ls += __shfl_xor(ls, 1); ls += __shfl_xor(ls, 2);

    float pc = 0.0f, lc = 0.0f, np = 0.0f;
    if (j == 0) {
        long long ag = (long long)blockIdx.x * TILE + aIdx;
        if (ag < nAnchor) {
            float conf = -cs;
            bool neg = (t0[aIdx] != 0.0f);
            bool pos = (posf[aIdx] != 0);
            unsigned key = neg ? f2k(conf) : 0u;
            keys[ag] = key;
            if (neg)
                atomicAdd(&hist[((blockIdx.x & (NSHARD - 1)) << 16) + (key >> 16)], 1u);
            if (pos) { pc = conf; lc = ls; np = 1.0f; }
        }
    }
    #pragma unroll
    for (int off = 1; off < 64; off <<= 1) {
        pc += __shfl_xor(pc, off);
        lc += __shfl_xor(lc, off);
        np += __shfl_xor(np, off);
    }
    int wv = tid >> 6;
    if ((tid & 63) == 0) { rbuf[wv*3+0] = pc; rbuf[wv*3+1] = lc; rbuf[wv*3+2] = np; }
    __syncthreads();
    if (tid == 0) {
        float P = 0.0f, L = 0.0f, Np = 0.0f;
        for (int w = 0; w < 4; ++w) { P += rbuf[w*3]; L += rbuf[w*3+1]; Np += rbuf[w*3+2]; }
        if (Np > 0.0f || P != 0.0f || L != 0.0f) {
            atomAddD(&sc->pos_sum, (double)P);
            atomAddD(&sc->loc_sum, (double)L);
            atomicAdd(&sc->npos, (unsigned)(Np + 0.5f));
        }
    }
}

// ---------------- radix-select level 1: pick 16-bit prefix ----------------
__global__ void kSel1(const unsigned* __restrict__ hist, Scalars* __restrict__ sc)
{
    __shared__ unsigned chunk[256];
    int t = threadIdx.x;
    unsigned s = 0;
    for (int b = t * 256; b < t * 256 + 256; ++b) {
        unsigned cb = 0;
        #pragma unroll
        for (int sh = 0; sh < NSHARD; ++sh) cb += hist[sh * 65536 + b];
        s += cb;
    }
    chunk[t] = s;
    __syncthreads();
    if (t == 0) {
        unsigned npos = sc->npos;
        unsigned K = (unsigned)(NEG_POS_RATIO_F * (float)npos);
        unsigned long long totalNeg = 0;
        for (int u = 0; u < 256; ++u) totalNeg += chunk[u];
        if (K == 0) {
            sc->T = 0xFFFFFFFFu; sc->mode = 1;           // take nothing
        } else if ((unsigned long long)K >= totalNeg) {
            sc->T = 0u; sc->mode = 1;                    // take all negatives
        } else {
            unsigned long long cum = 0;
            int c = 255;
            for (; c >= 0; --c) { if (cum + chunk[c] >= K) break; cum += chunk[c]; }
            int b = c * 256 + 255;
            for (;; --b) {
                unsigned cb = 0;
                for (int sh = 0; sh < NSHARD; ++sh) cb += hist[sh * 65536 + b];
                if (cum + cb >= K) break;
                cum += cb;
            }
            sc->selP = (unsigned)b;
            sc->K1 = K - (unsigned)cum;
            sc->mode = 0;
        }
    }
}

// ---------------- level-2 histogram (low 16 bits within prefix) ----------------
__global__ __launch_bounds__(256) void kHist2(
    const unsigned* __restrict__ keys, unsigned* __restrict__ hist2,
    const Scalars* __restrict__ sc, int n)
{
    if (sc->mode != 0) return;
    unsigned P = sc->selP;
    int i = (blockIdx.x * 256 + threadIdx.x) * 4;
    if (i + 3 < n) {
        uint4 k4 = *reinterpret_cast<const uint4*>(keys + i);
        unsigned kk[4] = {k4.x, k4.y, k4.z, k4.w};
        #pragma unroll
        for (int l = 0; l < 4; ++l)
            if (kk[l] != 0u && (kk[l] >> 16) == P) atomicAdd(&hist2[kk[l] & 0xFFFFu], 1u);
    } else {
        for (int l = 0; l < 4 && i + l < n; ++l) {
            unsigned k = keys[i + l];
            if (k != 0u && (k >> 16) == P) atomicAdd(&hist2[k & 0xFFFFu], 1u);
        }
    }
}

// ---------------- radix-select level 2: exact threshold ----------------
__global__ void kSel2(const unsigned* __restrict__ hist2, Scalars* __restrict__ sc)
{
    __shared__ unsigned chunk[256];
    if (sc->mode != 0) return;   // uniform across block
    int t = threadIdx.x;
    unsigned s = 0;
    for (int b = t * 256; b < t * 256 + 256; ++b) s += hist2[b];
    chunk[t] = s;
    __syncthreads();
    if (t == 0) {
        unsigned K1 = sc->K1;
        unsigned long long cum = 0;
        int c = 255;
        for (; c >= 0; --c) { if (cum + chunk[c] >= K1) break; cum += chunk[c]; }
        int b = c * 256 + 255;
        for (;; --b) { unsigned cb = hist2[b]; if (cum + cb >= K1) break; cum += cb; }
        unsigned T = (sc->selP << 16) | (unsigned)b;
        unsigned R = K1 - (unsigned)cum;       // ties taken at exactly T
        sc->T = T;
        sc->neg_sum = (double)R * (double)k2f(T);
    }
}

// ---------------- sum conf over keys strictly above threshold ----------------
__global__ __launch_bounds__(256) void kNegSum(
    const unsigned* __restrict__ keys, Scalars* __restrict__ sc, int n)
{
    unsigned T = sc->T;
    int i = (blockIdx.x * 256 + threadIdx.x) * 4;
    double s = 0.0;
    if (i + 3 < n) {
        uint4 k4 = *reinterpret_cast<const uint4*>(keys + i);
        unsigned kk[4] = {k4.x, k4.y, k4.z, k4.w};
        #pragma unroll
        for (int l = 0; l < 4; ++l)
            if (kk[l] > T) s += (double)k2f(kk[l]);
    } else {
        for (int l = 0; l < 4 && i + l < n; ++l) {
            unsigned k = keys[i + l];
            if (k > T) s += (double)k2f(k);
        }
    }
    #pragma unroll
    for (int off = 1; off < 64; off <<= 1) s += __shfl_xor(s, off);
    __shared__ double wbuf[4];
    if ((threadIdx.x & 63) == 0) wbuf[threadIdx.x >> 6] = s;
    __syncthreads();
    if (threadIdx.x == 0) {
        double tot = wbuf[0] + wbuf[1] + wbuf[2] + wbuf[3];
        if (tot != 0.0) atomAddD(&sc->neg_sum, tot);
    }
}

// ---------------- final scalar ----------------
__global__ void kFinal(const Scalars* __restrict__ sc, float* __restrict__ out)
{
    unsigned np = sc->npos;
    double denom = (double)(np > 0u ? np : 1u);
    out[0] = (float)((sc->pos_sum + sc->neg_sum + sc->loc_sum) / denom);
}

extern "C" void kernel_launch(void* const* d_in, const int* in_sizes, int n_in,
                              void* d_out, int out_size, void* d_ws, size_t ws_size,
                              hipStream_t stream)
{
    const float* yp = (const float*)d_in[0];
    const float* yt = (const float*)d_in[1];
    const int nTot = in_sizes[0];
    const int nAnchor = nTot / SLOT;

    char* ws = (char*)d_ws;
    size_t kb = ((size_t)nAnchor * 4 + 255) & ~(size_t)255;
    unsigned* keys  = (unsigned*)ws;
    unsigned* hist  = (unsigned*)(ws + kb);
    unsigned* hist2 = (unsigned*)(ws + kb + (size_t)NSHARD * 65536 * 4);
    Scalars*  sc    = (Scalars*)(ws + kb + (size_t)NSHARD * 65536 * 4 + 65536 * 4);
    size_t zlen = (size_t)NSHARD * 65536 * 4 + 65536 * 4 + sizeof(Scalars);

    hipMemsetAsync(ws + kb, 0, zlen, stream);

    int gA = (nAnchor + TILE - 1) / TILE;
    kMain<<<gA, 256, 0, stream>>>(yp, yt, keys, hist, sc, nAnchor);
    kSel1<<<1, 256, 0, stream>>>(hist, sc);
    int nq = (nAnchor + 3) / 4;
    int g4 = (nq + 255) / 256;
    kHist2<<<g4, 256, 0, stream>>>(keys, hist2, sc, nAnchor);
    kSel2<<<1, 256, 0, stream>>>(hist2, sc);
    kNegSum<<<g4, 256, 0, stream>>>(keys, sc, nAnchor);
    kFinal<<<1, 1, 0, stream>>>(sc, (float*)d_out);
}

// Round 3
// 1055.908 us; speedup vs baseline: 1.4438x; 1.4438x over previous
//
#include <hip/hip_runtime.h>
#include <hip/hip_bf16.h>

// SSD multibox loss, R3 (= R2 resubmit after infra failure; tn/pn UB fixed).
// Changes vs R1 (which stalled at 1.48 TB/s effective, VALUBusy 17%, HBM 10%):
//  - kMain: ZERO global atomics (per-block partials, reduced by kReduceP)
//  - TILE 64 -> 256 anchors/block (6141 blocks), LDS only holds per-anchor
//    results (~6 KB) instead of all elementwise products (22.5 KB)
//  - 2-deep manual prefetch in the stream loop
//  - selection: contention-free level-1 histogram (per-block LDS rows),
//    then 8/16/8 radix refine over the 6.3 MB key array.

#define SLOT 85
#define NCLS 81
#define TILE 256
#define TELEM (TILE * SLOT)      // 21760 floats per tensor per tile
#define NEG_POS_RATIO_F 3.0f
#define NH1B 512                 // kHist1 block count
#define NSB  512                 // generic streaming-pass block count

struct Scalars {
    double pos_sum, loc_sum, neg_sum;
    unsigned npos, mode, P1, K1, P2, K2, T, pad;
};

__device__ inline unsigned f2k(float f) {
    unsigned b = __float_as_uint(f);
    return (b & 0x80000000u) ? ~b : (b | 0x80000000u);
}
__device__ inline float k2f(unsigned k) {
    unsigned b = (k & 0x80000000u) ? (k & 0x7FFFFFFFu) : ~k;
    return __uint_as_float(b);
}

// ---------------- main streaming pass ----------------
__global__ __launch_bounds__(256) void kMain(
    const float* __restrict__ yp, const float* __restrict__ yt,
    unsigned* __restrict__ keys,
    double* __restrict__ pPos, double* __restrict__ pLoc, unsigned* __restrict__ pNp,
    int nAnchor)
{
    __shared__ unsigned clsw[TILE];                 // class index of the one-hot slot
    __shared__ float    conf[TILE];                 // yt[cls]*yp[cls]
    __shared__ alignas(16) float loc4[TILE][4];     // per-coord smooth-L1
    __shared__ double   rbuf[8];
    __shared__ unsigned rnp[4];

    const int tid = threadIdx.x;
    const long long base   = (long long)blockIdx.x * TELEM;
    const long long totalE = (long long)nAnchor * SLOT;

    clsw[tid] = 0xFFFFFFFFu;
    conf[tid] = 0.0f;
    *reinterpret_cast<float4*>(loc4[tid]) = make_float4(0.f, 0.f, 0.f, 0.f);
    __syncthreads();

    if (base + TELEM <= totalE) {
        // ---- fast path: full tile, no bounds checks, 2-deep prefetch ----
        const float* tp = yt + base;
        const float* pp = yp + base;
        int i = tid * 4;
        int a = i / SLOT;
        int c = i - a * SLOT;
        float4 tc = *reinterpret_cast<const float4*>(tp + i);
        float4 pc = *reinterpret_cast<const float4*>(pp + i);
        bool have = true;
        while (have) {
            const int inext = i + 1024;
            const bool hnext = inext < TELEM;
            float4 tn = tc, pn = pc;
            if (hnext) {
                tn = *reinterpret_cast<const float4*>(tp + inext);
                pn = *reinterpret_cast<const float4*>(pp + inext);
            }
            // process current quad (elements i..i+3 -> anchor a.., slot c..)
            {
                const float tv[4] = {tc.x, tc.y, tc.z, tc.w};
                const float pv[4] = {pc.x, pc.y, pc.z, pc.w};
                #pragma unroll
                for (int l = 0; l < 4; ++l) {
                    int cl = c + l, al = a;
                    if (cl >= SLOT) { cl -= SLOT; al += 1; }
                    const float t = tv[l], p = pv[l];
                    if (cl < NCLS) {
                        if (t != 0.0f) { conf[al] = t * p; clsw[al] = (unsigned)cl; }
                    } else {
                        const float d = p - t;
                        const float ad = fabsf(d);
                        loc4[al][cl - NCLS] = (ad < 1.0f) ? 0.5f * d * d : (ad - 0.5f);
                    }
                }
            }
            i = inext; tc = tn; pc = pn; have = hnext;
            a += 12; c += 4;
            if (c >= SLOT) { c -= SLOT; a += 1; }
        }
    } else {
        // ---- generic tail path (not taken for the bench shape) ----
        for (int i = tid * 4; i < TELEM; i += 1024) {
            int a = i / SLOT, c = i - a * SLOT;
            #pragma unroll
            for (int l = 0; l < 4; ++l) {
                const long long g = base + i + l;
                if (g >= totalE) break;
                int cl = c + l, al = a;
                if (cl >= SLOT) { cl -= SLOT; al += 1; }
                const float t = yt[g], p = yp[g];
                if (cl < NCLS) {
                    if (t != 0.0f) { conf[al] = t * p; clsw[al] = (unsigned)cl; }
                } else {
                    const float d = p - t;
                    const float ad = fabsf(d);
                    loc4[al][cl - NCLS] = (ad < 1.0f) ? 0.5f * d * d : (ad - 0.5f);
                }
            }
        }
    }
    __syncthreads();

    // ---- per-anchor results: one thread per anchor ----
    const long long ga = (long long)blockIdx.x * TILE + tid;
    double myPos = 0.0, myLoc = 0.0;
    unsigned myNp = 0;
    if (ga < nAnchor) {
        const unsigned cw = clsw[tid];
        const float cf = -conf[tid];                 // conf loss = -(yt . yp)
        keys[ga] = (cw == 0u) ? f2k(cf) : 0u;        // negatives get a sortable key
        if (cw != 0xFFFFFFFFu && cw > 0u) {          // positive anchor
            const float l4 = (loc4[tid][0] + loc4[tid][1]) + (loc4[tid][2] + loc4[tid][3]);
            myPos = (double)cf;
            myLoc = (double)l4;
            myNp = 1u;
        }
    }
    #pragma unroll
    for (int off = 1; off < 64; off <<= 1) {
        myPos += __shfl_xor(myPos, off);
        myLoc += __shfl_xor(myLoc, off);
        myNp  += __shfl_xor(myNp,  off);
    }
    const int w = tid >> 6;
    if ((tid & 63) == 0) { rbuf[w] = myPos; rbuf[4 + w] = myLoc; rnp[w] = myNp; }
    __syncthreads();
    if (tid == 0) {
        pPos[blockIdx.x] = (rbuf[0] + rbuf[1]) + (rbuf[2] + rbuf[3]);
        pLoc[blockIdx.x] = (rbuf[4] + rbuf[5]) + (rbuf[6] + rbuf[7]);
        pNp[blockIdx.x]  = rnp[0] + rnp[1] + rnp[2] + rnp[3];
    }
}

// ---------------- reduce per-block partials (no atomics anywhere) ----------------
__global__ __launch_bounds__(256) void kReduceP(
    const double* __restrict__ pPos, const double* __restrict__ pLoc,
    const unsigned* __restrict__ pNp, Scalars* __restrict__ sc, int nblk)
{
    double sp = 0.0, sl = 0.0;
    unsigned np = 0;
    for (int i = threadIdx.x; i < nblk; i += 256) {
        sp += pPos[i]; sl += pLoc[i]; np += pNp[i];
    }
    #pragma unroll
    for (int off = 1; off < 64; off <<= 1) {
        sp += __shfl_xor(sp, off);
        sl += __shfl_xor(sl, off);
        np += __shfl_xor(np, off);
    }
    __shared__ double b0[4], b1[4];
    __shared__ unsigned b2[4];
    if ((threadIdx.x & 63) == 0) {
        b0[threadIdx.x >> 6] = sp; b1[threadIdx.x >> 6] = sl; b2[threadIdx.x >> 6] = np;
    }
    __syncthreads();
    if (threadIdx.x == 0) {
        sc->pos_sum = b0[0] + b0[1] + b0[2] + b0[3];
        sc->loc_sum = b1[0] + b1[1] + b1[2] + b1[3];
        sc->npos    = b2[0] + b2[1] + b2[2] + b2[3];
        sc->neg_sum = 0.0;
    }
}

// ---------------- level-1 histogram: top 8 bits, per-block private rows ----------------
__global__ __launch_bounds__(256) void kHist1(
    const unsigned* __restrict__ keys, unsigned* __restrict__ h1p, int n)
{
    __shared__ unsigned h[256];
    h[threadIdx.x] = 0;
    __syncthreads();
    const long long stride = (long long)NH1B * 1024;
    for (long long i = ((long long)blockIdx.x * 256 + threadIdx.x) * 4; i < n; i += stride) {
        if (i + 3 < n) {
            const uint4 k4 = *reinterpret_cast<const uint4*>(keys + i);
            if (k4.x) atomicAdd(&h[k4.x >> 24], 1u);
            if (k4.y) atomicAdd(&h[k4.y >> 24], 1u);
            if (k4.z) atomicAdd(&h[k4.z >> 24], 1u);
            if (k4.w) atomicAdd(&h[k4.w >> 24], 1u);
        } else {
            for (int l = 0; l < 4 && i + l < n; ++l) {
                const unsigned k = keys[i + l];
                if (k) atomicAdd(&h[k >> 24], 1u);
            }
        }
    }
    __syncthreads();
    h1p[blockIdx.x * 256 + threadIdx.x] = h[threadIdx.x];   // private row, no atomics
}

__global__ __launch_bounds__(256) void kScan1(
    const unsigned* __restrict__ h1p, Scalars* __restrict__ sc)
{
    __shared__ unsigned col[256];
    const int t = threadIdx.x;
    unsigned s = 0;
    for (int b = 0; b < NH1B; ++b) s += h1p[b * 256 + t];  // coalesced per-wave
    col[t] = s;
    __syncthreads();
    if (t == 0) {
        const unsigned K = (unsigned)(NEG_POS_RATIO_F * (float)sc->npos);
        unsigned long long totalNeg = 0;
        for (int u = 0; u < 256; ++u) totalNeg += col[u];
        if (K == 0u)                                { sc->mode = 1u; sc->T = 0xFFFFFFFFu; }
        else if ((unsigned long long)K >= totalNeg) { sc->mode = 1u; sc->T = 0u; }
        else {
            unsigned long long cum = 0; int b = 255;
            for (; b >= 0; --b) { if (cum + col[b] >= K) break; cum += col[b]; }
            sc->mode = 0u; sc->P1 = (unsigned)b; sc->K1 = K - (unsigned)cum;
        }
    }
}

// ---------------- level-2: next 16 bits within P1 (sparse bins, no contention) ----------------
__global__ __launch_bounds__(256) void kHist2(
    const unsigned* __restrict__ keys, unsigned* __restrict__ h2,
    const Scalars* __restrict__ sc, int n)
{
    if (sc->mode) return;
    const unsigned P1 = sc->P1;
    const long long stride = (long long)NSB * 1024;
    for (long long i = ((long long)blockIdx.x * 256 + threadIdx.x) * 4; i < n; i += stride) {
        if (i + 3 < n) {
            const uint4 k4 = *reinterpret_cast<const uint4*>(keys + i);
            if (k4.x && (k4.x >> 24) == P1) atomicAdd(&h2[(k4.x >> 8) & 0xFFFFu], 1u);
            if (k4.y && (k4.y >> 24) == P1) atomicAdd(&h2[(k4.y >> 8) & 0xFFFFu], 1u);
            if (k4.z && (k4.z >> 24) == P1) atomicAdd(&h2[(k4.z >> 8) & 0xFFFFu], 1u);
            if (k4.w && (k4.w >> 24) == P1) atomicAdd(&h2[(k4.w >> 8) & 0xFFFFu], 1u);
        } else {
            for (int l = 0; l < 4 && i + l < n; ++l) {
                const unsigned k = keys[i + l];
                if (k && (k >> 24) == P1) atomicAdd(&h2[(k >> 8) & 0xFFFFu], 1u);
            }
        }
    }
}

__global__ __launch_bounds__(256) void kScan2(
    const unsigned* __restrict__ h2, Scalars* __restrict__ sc)
{
    if (sc->mode) return;
    __shared__ unsigned chunk[256];
    const int t = threadIdx.x;
    unsigned s = 0;
    const unsigned* p = h2 + t * 256;
    for (int u = 0; u < 256; ++u) s += p[u];
    chunk[t] = s;
    __syncthreads();
    if (t == 0) {
        const unsigned K1 = sc->K1;
        unsigned long long cum = 0; int cg = 255;
        for (; cg >= 0; --cg) { if (cum + chunk[cg] >= K1) break; cum += chunk[cg]; }
        int b = cg * 256 + 255;
        for (;; --b) { const unsigned cb = h2[b]; if (cum + cb >= K1) break; cum += cb; }
        sc->P2 = (sc->P1 << 16) | (unsigned)b;   // 24-bit prefix
        sc->K2 = K1 - (unsigned)cum;
    }
}

// ---------------- level-3: final 8 bits ----------------
__global__ __launch_bounds__(256) void kHist3(
    const unsigned* __restrict__ keys, unsigned* __restrict__ h3,
    const Scalars* __restrict__ sc, int n)
{
    if (sc->mode) return;
    const unsigned P2 = sc->P2;
    const long long stride = (long long)NSB * 1024;
    for (long long i = ((long long)blockIdx.x * 256 + threadIdx.x) * 4; i < n; i += stride) {
        if (i + 3 < n) {
            const uint4 k4 = *reinterpret_cast<const uint4*>(keys + i);
            if ((k4.x >> 8) == P2) atomicAdd(&h3[k4.x & 0xFFu], 1u);
            if ((k4.y >> 8) == P2) atomicAdd(&h3[k4.y & 0xFFu], 1u);
            if ((k4.z >> 8) == P2) atomicAdd(&h3[k4.z & 0xFFu], 1u);
            if ((k4.w >> 8) == P2) atomicAdd(&h3[k4.w & 0xFFu], 1u);
        } else {
            for (int l = 0; l < 4 && i + l < n; ++l) {
                const unsigned k = keys[i + l];
                if ((k >> 8) == P2) atomicAdd(&h3[k & 0xFFu], 1u);
            }
        }
    }
}

__global__ void kScan3(const unsigned* __restrict__ h3, Scalars* __restrict__ sc)
{
    if (threadIdx.x == 0 && sc->mode == 0u) {
        const unsigned K2 = sc->K2;
        unsigned long long cum = 0; int b = 255;
        for (; b >= 0; --b) { const unsigned cb = h3[b]; if (cum + cb >= K2) break; cum += cb; }
        const unsigned T = (sc->P2 << 8) | (unsigned)b;
        const unsigned R = K2 - (unsigned)cum;       // ties taken at exactly T
        sc->T = T;
        sc->neg_sum = (double)R * (double)k2f(T);
    }
}

// ---------------- sum conf over keys strictly above threshold ----------------
__global__ __launch_bounds__(256) void kNegSum(
    const unsigned* __restrict__ keys, Scalars* __restrict__ sc, int n)
{
    const unsigned T = sc->T;
    double s = 0.0;
    const long long stride = (long long)NSB * 1024;
    for (long long i = ((long long)blockIdx.x * 256 + threadIdx.x) * 4; i < n; i += stride) {
        if (i + 3 < n) {
            const uint4 k4 = *reinterpret_cast<const uint4*>(keys + i);
            if (k4.x > T) s += (double)k2f(k4.x);
            if (k4.y > T) s += (double)k2f(k4.y);
            if (k4.z > T) s += (double)k2f(k4.z);
            if (k4.w > T) s += (double)k2f(k4.w);
        } else {
            for (int l = 0; l < 4 && i + l < n; ++l) {
                const unsigned k = keys[i + l];
                if (k > T) s += (double)k2f(k);
            }
        }
    }
    #pragma unroll
    for (int off = 1; off < 64; off <<= 1) s += __shfl_xor(s, off);
    __shared__ double wb[4];
    if ((threadIdx.x & 63) == 0) wb[threadIdx.x >> 6] = s;
    __syncthreads();
    if (threadIdx.x == 0) {
        const double tot = (wb[0] + wb[1]) + (wb[2] + wb[3]);
        if (tot != 0.0) unsafeAtomicAdd(&sc->neg_sum, tot);  // ~NSB atomics total
    }
}

__global__ void kFinal(const Scalars* __restrict__ sc, float* __restrict__ out)
{
    const unsigned np = sc->npos;
    const double denom = (double)(np > 0u ? np : 1u);
    out[0] = (float)((sc->pos_sum + sc->neg_sum + sc->loc_sum) / denom);
}

extern "C" void kernel_launch(void* const* d_in, const int* in_sizes, int n_in,
                              void* d_out, int out_size, void* d_ws, size_t ws_size,
                              hipStream_t stream)
{
    const float* yp = (const float*)d_in[0];
    const float* yt = (const float*)d_in[1];
    const int nTot = in_sizes[0];
    const int nAnchor = nTot / SLOT;
    const int gA = (nAnchor + TILE - 1) / TILE;

    char* ws = (char*)d_ws;
    size_t off = 0;
    auto alloc = [&](size_t bytes) { size_t o = off; off = (off + bytes + 255) & ~(size_t)255; return o; };

    const size_t oKeys = alloc((size_t)nAnchor * 4);
    const size_t oH2   = alloc(65536 * 4);
    const size_t oH3   = alloc(256 * 4);
    const size_t oSc   = alloc(sizeof(Scalars));
    const size_t oH1p  = alloc((size_t)NH1B * 256 * 4);
    const size_t oPPos = alloc((size_t)gA * 8);
    const size_t oPLoc = alloc((size_t)gA * 8);
    const size_t oPNp  = alloc((size_t)gA * 4);

    unsigned* keys = (unsigned*)(ws + oKeys);
    unsigned* h2   = (unsigned*)(ws + oH2);
    unsigned* h3   = (unsigned*)(ws + oH3);
    Scalars*  sc   = (Scalars*)(ws + oSc);
    unsigned* h1p  = (unsigned*)(ws + oH1p);
    double*   pPos = (double*)(ws + oPPos);
    double*   pLoc = (double*)(ws + oPLoc);
    unsigned* pNp  = (unsigned*)(ws + oPNp);

    // zero h2 + h3 (+ the Scalars block; covers alignment padding too)
    hipMemsetAsync(ws + oH2, 0, oSc + sizeof(Scalars) - oH2, stream);

    kMain   <<<gA,   256, 0, stream>>>(yp, yt, keys, pPos, pLoc, pNp, nAnchor);
    kReduceP<<<1,    256, 0, stream>>>(pPos, pLoc, pNp, sc, gA);
    kHist1  <<<NH1B, 256, 0, stream>>>(keys, h1p, nAnchor);
    kScan1  <<<1,    256, 0, stream>>>(h1p, sc);
    kHist2  <<<NSB,  256, 0, stream>>>(keys, h2, sc, nAnchor);
    kScan2  <<<1,    256, 0, stream>>>(h2, sc);
    kHist3  <<<NSB,  256, 0, stream>>>(keys, h3, sc, nAnchor);
    kScan3  <<<1,    1,   0, stream>>>(h3, sc);
    kNegSum <<<NSB,  256, 0, stream>>>(keys, sc, nAnchor);
    kFinal  <<<1,    1,   0, stream>>>(sc, (float*)d_out);
}